// Round 13
// baseline (295.750 us; speedup 1.0000x reference)
//
#include <hip/hip_runtime.h>
#include <hip/hip_bf16.h>

typedef __attribute__((ext_vector_type(8))) short short8x;   // 8 x bf16 (4 VGPR) MFMA A/B frag
typedef __attribute__((ext_vector_type(4))) float f32x4;     // MFMA C/D frag

__device__ __forceinline__ ushort f2bf(float f){
  union { __hip_bfloat16 b; ushort u; } cvt;
  cvt.b = __float2bfloat16(f);                // RNE
  return cvt.u;
}

// ---------------- elementwise fp32 -> bf16 (optional scale) ----------------
__global__ __launch_bounds__(256) void cvt_kernel(const float* __restrict__ in, ushort* __restrict__ out,
                                                  long n, float scale){
  long i = ((long)blockIdx.x * 256 + threadIdx.x) * 4;
  if (i >= n) return;
  float4 v = *(const float4*)(in + i);
  ushort4 o;
  o.x = f2bf(v.x * scale); o.y = f2bf(v.y * scale); o.z = f2bf(v.z * scale); o.w = f2bf(v.w * scale);
  *(ushort4*)(out + i) = o;
}

// ---------------- 256x256 bf16 GEMM: C = A[M,K] * BT[N,K]^T, BK=64, 8 waves -----------------
// m201-inspired geometry on the flash12-proven pipeline skeleton. Per K-tile:
// counted vmcnt(8) -> barrier -> 4 sub-phases {12 ds_read_b128 -> lgkmcnt(0) -> setprio(1) ->
// 16 MFMA -> setprio(0)} -> barrier -> stage(kt+2). LDS [256][64] tiles, granule XOR swizzle
// g^=(row&7) on BOTH sides (pre-swizzled global source + swizzled read): 128B rows -> banks
// depend only on swizzled granule -> 2 lanes/bank-quad = conflict-free.
// Wave w: wm=w>>2 (2 M-halves of 128), wn=w&3 (4 N-strips of 64); acc[8][4] = 128 VGPR.
// Grid: x = N/256, y = M/256; XCD swizzle (nwg % 8 == 0 for all launches here).
template<int OUTBF>
__global__ __launch_bounds__(512, 1)
void gemm256(const ushort* __restrict__ A, const ushort* __restrict__ BT, void* __restrict__ Cv,
             int K, int lda, int ldb, int ldc, float scale)
{
  __shared__ __align__(16) ushort As[2][256 * 64];   // 32KB x2
  __shared__ __align__(16) ushort Bs[2][256 * 64];   // 32KB x2
  const int tid = threadIdx.x, lane = tid & 63, w = tid >> 6;
  const int lq = lane & 15, q4 = lane >> 4;
  const int wm = w >> 2, wn = w & 3;

  int lin = blockIdx.x + gridDim.x * blockIdx.y;
  const int cpx = (gridDim.x * gridDim.y) >> 3;
  lin = (lin & 7) * cpx + (lin >> 3);
  const int bx = lin % gridDim.x, by = lin / gridDim.x;
  const long arow = (long)by * 256, brow = (long)bx * 256;

  // staging: thread t covers LDS row s*64 + (t>>3), granule position t&7, which must hold
  // global granule (t&7) ^ ((t>>3)&7)  [row&7 == (t>>3)&7 since s*64 = 0 mod 8]
  const int srow = tid >> 3;                       // 0..63
  const int sg = (tid & 7) ^ (srow & 7);
  const ushort* Abase = A + (arow + srow) * (long)lda + sg * 8;
  const ushort* Bbase = BT + (brow + srow) * (long)ldb + sg * 8;
  const int dof = w * 512;                         // lane-linear wave slice within segment

  auto stage = [&](int buf, int kt){
    const long kc = (long)kt * 64;
#pragma unroll
    for (int s = 0; s < 4; ++s){
      __builtin_amdgcn_global_load_lds(
          (const __attribute__((address_space(1))) void*)(Abase + (long)(s * 64) * lda + kc),
          (__attribute__((address_space(3))) void*)&As[buf][s * 4096 + dof], 16, 0, 0);
      __builtin_amdgcn_global_load_lds(
          (const __attribute__((address_space(1))) void*)(Bbase + (long)(s * 64) * ldb + kc),
          (__attribute__((address_space(3))) void*)&Bs[buf][s * 4096 + dof], 16, 0, 0);
    }
  };

  const f32x4 z4 = {0.f, 0.f, 0.f, 0.f};
  f32x4 acc[8][4];
#pragma unroll
  for (int i = 0; i < 8; i++)
#pragma unroll
    for (int j = 0; j < 4; j++) acc[i][j] = z4;

  const int rx = lq & 7;                           // read-side swizzle key (row&7 == lq&7)
  const int arb = wm * 128;                        // wave A-row base in tile
  const int brb = wn * 64;                         // wave B-row base in tile

  const int nk = K >> 6;
  stage(0, 0);
  stage(1, 1);                                     // nk >= 2 always here

#pragma unroll 1
  for (int kt = 0; kt < nk; ++kt){
    if (kt == nk - 1) asm volatile("s_waitcnt vmcnt(0)" ::: "memory");
    else              asm volatile("s_waitcnt vmcnt(8)" ::: "memory");
    __syncthreads();
    const int buf = kt & 1;

#pragma unroll
    for (int q = 0; q < 4; ++q){                   // quadrant: mi = q&1 (M half), nj = q>>1 (N half)
      const int mi = q & 1, nj = q >> 1;
      short8x af[4][2], bf[2][2];
#pragma unroll
      for (int i2 = 0; i2 < 4; ++i2){
        const int R = arb + (mi * 4 + i2) * 16 + lq;
#pragma unroll
        for (int kk = 0; kk < 2; ++kk)
          af[i2][kk] = *(const short8x*)&As[buf][R * 64 + (((kk * 4 + q4) ^ rx) * 8)];
      }
#pragma unroll
      for (int j2 = 0; j2 < 2; ++j2){
        const int R = brb + (nj * 2 + j2) * 16 + lq;
#pragma unroll
        for (int kk = 0; kk < 2; ++kk)
          bf[j2][kk] = *(const short8x*)&Bs[buf][R * 64 + (((kk * 4 + q4) ^ rx) * 8)];
      }
      asm volatile("s_waitcnt lgkmcnt(0)" ::: "memory");
      __builtin_amdgcn_sched_barrier(0);
      __builtin_amdgcn_s_setprio(1);
#pragma unroll
      for (int kk = 0; kk < 2; ++kk)
#pragma unroll
        for (int i2 = 0; i2 < 4; ++i2)
#pragma unroll
          for (int j2 = 0; j2 < 2; ++j2)
            acc[mi * 4 + i2][nj * 2 + j2] =
                __builtin_amdgcn_mfma_f32_16x16x32_bf16(af[i2][kk], bf[j2][kk],
                                                        acc[mi * 4 + i2][nj * 2 + j2], 0, 0, 0);
      __builtin_amdgcn_s_setprio(0);
    }
    __syncthreads();
    if (kt + 2 < nk) stage(buf, kt + 2);
  }

  const long crowb = arow + wm * 128;
  const long ccolb = brow + wn * 64;
#pragma unroll
  for (int i = 0; i < 8; i++)
#pragma unroll
    for (int j = 0; j < 4; j++)
#pragma unroll
      for (int r = 0; r < 4; r++){
        const long row = crowb + i * 16 + q4 * 4 + r;
        const long col = ccolb + j * 16 + lq;
        const float v = acc[i][j][r] * scale;
        if (OUTBF) ((ushort*)Cv)[row * ldc + col] = f2bf(v);
        else       ((float*)Cv)[row * ldc + col] = v;
      }
}

// ---------------- flash attention v12: 4 waves x 32 q-rows, KVBLK=64, 2 blocks/CU -----------
// (unchanged from round 12: 77 us, verified)
__global__ __launch_bounds__(256, 1)
void flash12_kernel(const ushort* __restrict__ q, const ushort* __restrict__ k,
                    const ushort* __restrict__ vT, ushort* __restrict__ attnO)
{
  __shared__ __align__(16) ushort Kb[2][64 * 128];   // [t][d] swizzled granules, 16KB each
  __shared__ __align__(16) ushort Vb[2][128 * 64];   // [d][t] swizzled granules, 16KB each
  __shared__ __align__(16) ushort Pl[4][2][16][64];  // [w][si][s][t], granule-XOR swizzled, 16KB

  const int tid = threadIdx.x, lane = tid & 63, w = tid >> 6;   // w = 0..3
  const int lq = lane & 15, q4 = lane >> 4;

  const int i = blockIdx.x;
  const int pr = i >> 8;                     // 0 = primary (heavy), 1 = secondary (light)
  const int ii = i & 255;
  const int xcd = ii & 7;
  const int bh = xcd * 4 + ((ii >> 3) & 3);
  const int j = ii >> 5;                     // 0..7
  const int strip = pr ? j : (15 - j);       // strips of 128 q-rows
  const int b = bh & 1, h = bh >> 1;

  const int nt = 2 * (strip + 1);            // 64-wide t-tiles staged by this block
  const int wdiag = strip * 2 + (w >> 1);    // wave's diagonal tile
  const int moff = (w & 1) * 32;             // wave's row offset within diag tile

  const ushort* kb_ = k + (long)b * 2048 * 2048 + h * 128;        // row t stride 2048
  const ushort* vb_ = vT + (long)h * 128 * 4096 + (long)b * 2048; // row d stride 4096

  const int krow0 = w * 4 + (lane >> 4);                          // is adds 16
  const int kg = (lane & 15) ^ (krow0 & 7);
  const ushort* kbase = kb_ + (long)krow0 * 2048 + kg * 8;
  const int kofs0 = w * 512;                                      // is adds 2048

  const int drow0 = w * 8 + (lane >> 3);                          // is adds 32
  const int vg = (lane & 7) ^ (drow0 & 7);
  const ushort* vbase = vb_ + (long)drow0 * 4096 + vg * 8;
  const int vofs0 = w * 512;

  auto stage = [&](int buf, int tt){
    const ushort* kp = kbase + (long)tt * 64 * 2048;
    const ushort* vp = vbase + (long)tt * 64;
#pragma unroll
    for (int is = 0; is < 4; ++is){
      __builtin_amdgcn_global_load_lds((const __attribute__((address_space(1))) void*)(kp + (long)is * 16 * 2048),
          (__attribute__((address_space(3))) void*)&Kb[buf][kofs0 + is * 2048], 16, 0, 0);
      __builtin_amdgcn_global_load_lds((const __attribute__((address_space(1))) void*)(vp + (long)is * 32 * 4096),
          (__attribute__((address_space(3))) void*)&Vb[buf][vofs0 + is * 2048], 16, 0, 0);
    }
  };

  const f32x4 z4 = {0.f, 0.f, 0.f, 0.f};

  const int qrow0 = strip * 128 + w * 32;
  const long qgbase = (long)b * 2048 + qrow0;

  short8x qf[2][4];
#pragma unroll
  for (int si = 0; si < 2; si++){
    const ushort* qp = q + (qgbase + si * 16 + lq) * 2560 + h * 128 + q4 * 8;
#pragma unroll
    for (int ks = 0; ks < 4; ks++) qf[si][ks] = *(const short8x*)(qp + ks * 32);
  }

  f32x4 oacc[8][2];                          // [dt][si]  O^T[d][s]
#pragma unroll
  for (int dt = 0; dt < 8; dt++){ oacc[dt][0] = z4; oacc[dt][1] = z4; }
  float dsum[2] = {0.f, 0.f};

  const int prx = lq & 7;                    // Pl granule XOR key (per s-row)

  stage(0, 0);
  stage(1, 1);          // nt >= 2 always

#pragma unroll 1
  for (int tt = 0; tt < nt; ++tt){
    if (tt == nt - 1) asm volatile("s_waitcnt vmcnt(0)" ::: "memory");
    else              asm volatile("s_waitcnt vmcnt(8)" ::: "memory");
    __syncthreads();
    const int cur = tt & 1;

    if (tt <= wdiag){
      const bool diag = (tt == wdiag);
#pragma unroll
      for (int ti = 0; ti < 4; ++ti){
        const int r = ti * 16 + lq;
        const int rb = r * 128;
        const int rxk = r & 7;
        const short8x a0 = *(const short8x*)&Kb[cur][rb + (((q4) ^ rxk) * 8)];
        const short8x a1 = *(const short8x*)&Kb[cur][rb + (((4 + q4) ^ rxk) * 8)];
        const short8x a2 = *(const short8x*)&Kb[cur][rb + (((8 + q4) ^ rxk) * 8)];
        const short8x a3 = *(const short8x*)&Kb[cur][rb + (((12 + q4) ^ rxk) * 8)];
        const int cG = (ti * 2 + (q4 >> 1)) ^ prx;          // 16B-granule index, swizzled
        const int pco = cG * 8 + (q4 & 1) * 4;              // elem offset within row
#pragma unroll
        for (int si = 0; si < 2; ++si){
          f32x4 st = __builtin_amdgcn_mfma_f32_16x16x32_bf16(a0, qf[si][0], z4, 0, 0, 0);
          st = __builtin_amdgcn_mfma_f32_16x16x32_bf16(a1, qf[si][1], st, 0, 0, 0);
          st = __builtin_amdgcn_mfma_f32_16x16x32_bf16(a2, qf[si][2], st, 0, 0, 0);
          st = __builtin_amdgcn_mfma_f32_16x16x32_bf16(a3, qf[si][3], st, 0, 0, 0);
          ushort4 pb;
#pragma unroll
          for (int r4 = 0; r4 < 4; ++r4){
            const int tl = ti * 16 + q4 * 4 + r4;
            float p = exp2f(st[r4]);
            if (diag && tl > moff + si * 16 + lq) p = 0.f;
            dsum[si] += p;
            ((ushort*)&pb)[r4] = f2bf(p);
          }
          *(ushort4*)&Pl[w][si][lq][pco] = pb;
        }
      }
      asm volatile("s_waitcnt lgkmcnt(0)" ::: "memory");
      __builtin_amdgcn_sched_barrier(0);
      const short8x pf00 = *(const short8x*)&Pl[w][0][lq][(q4 ^ prx) * 8];
      const short8x pf01 = *(const short8x*)&Pl[w][0][lq][((4 + q4) ^ prx) * 8];
      const short8x pf10 = *(const short8x*)&Pl[w][1][lq][(q4 ^ prx) * 8];
      const short8x pf11 = *(const short8x*)&Pl[w][1][lq][((4 + q4) ^ prx) * 8];
      __builtin_amdgcn_sched_barrier(0);
#pragma unroll
      for (int dt = 0; dt < 8; ++dt){
        const int r = dt * 16 + lq;
        const int rb = r * 64;
        const int rxv = lq & 7;
        const short8x av0 = *(const short8x*)&Vb[cur][rb + (((q4) ^ rxv) * 8)];
        const short8x av1 = *(const short8x*)&Vb[cur][rb + (((4 + q4) ^ rxv) * 8)];
        oacc[dt][0] = __builtin_amdgcn_mfma_f32_16x16x32_bf16(av0, pf00, oacc[dt][0], 0, 0, 0);
        oacc[dt][0] = __builtin_amdgcn_mfma_f32_16x16x32_bf16(av1, pf01, oacc[dt][0], 0, 0, 0);
        oacc[dt][1] = __builtin_amdgcn_mfma_f32_16x16x32_bf16(av0, pf10, oacc[dt][1], 0, 0, 0);
        oacc[dt][1] = __builtin_amdgcn_mfma_f32_16x16x32_bf16(av1, pf11, oacc[dt][1], 0, 0, 0);
      }
    }
    __syncthreads();                        // all reads of buf[cur] complete
    if (tt + 2 < nt) stage(cur, tt + 2);    // overwrite buf[cur] = buf[(tt+2)&1]
  }

  float inv[2];
#pragma unroll
  for (int si = 0; si < 2; ++si){
    float d = dsum[si];
    d += __shfl_xor(d, 16);
    d += __shfl_xor(d, 32);
    inv[si] = 1.f / d;
  }

#pragma unroll
  for (int dt = 0; dt < 8; dt++)
#pragma unroll
    for (int si = 0; si < 2; si++){
      ushort4 o;
      o.x = f2bf(oacc[dt][si][0] * inv[si]);
      o.y = f2bf(oacc[dt][si][1] * inv[si]);
      o.z = f2bf(oacc[dt][si][2] * inv[si]);
      o.w = f2bf(oacc[dt][si][3] * inv[si]);
      *(ushort4*)(attnO + (qgbase + si * 16 + lq) * 2048 + h * 128 + dt * 16 + q4 * 4) = o;
    }
}

// ---------------- host launcher ----------------
extern "C" void kernel_launch(void* const* d_in, const int* in_sizes, int n_in,
                              void* d_out, int out_size, void* d_ws, size_t ws_size,
                              hipStream_t stream)
{
  const float* x   = (const float*)d_in[0];
  const float* Wd  = (const float*)d_in[1];
  const float* Wuk = (const float*)d_in[2];
  const float* Wuv = (const float*)d_in[3];
  const float* Wq  = (const float*)d_in[4];
  const float* Wo  = (const float*)d_in[5];
  float* out = (float*)d_out;
  ushort* ws = (ushort*)d_ws;

  ushort* xb    = ws + 0L;          // [4096][2048]
  ushort* wqdb  = ws + 8388608L;    // [2560][2048]: rows 0..2047 = Wq*(log2e/sqrt(128)), 2048..2559 = Wd
  ushort* wob   = ws + 13631488L;   // [2048(m)][2048(h,d)]
  ushort* wukb  = ws + 17825792L;   // [2048(h,d)][512(c)]
  ushort* wuvb  = ws + 18874368L;   // [2048(h,d)][512(c)]
  ushort* qlat  = ws + 19922944L;   // [4096][2560]: cols 0..2047 = q (pre-scaled), 2048..2559 = lat
  ushort* kb    = ws + 30408704L;   // [4096(b,t)][2048(h,d)]
  ushort* vTb   = ws + 38797312L;   // [2048(h,d)][4096(b,t)]
  ushort* attnO = ws + 47185920L;   // [4096(b,s)][2048(h,d)]

  // log2(e)/sqrt(128): folded into Wq so flash uses exp2 (identical softmax)
  const float QSCL = 0.12751744800f;

  cvt_kernel<<<8192, 256, 0, stream>>>(x,   xb,            8388608L, 1.0f);
  cvt_kernel<<<4096, 256, 0, stream>>>(Wq,  wqdb,          4194304L, QSCL);
  cvt_kernel<<<1024, 256, 0, stream>>>(Wd,  wqdb + 4194304L, 1048576L, 1.0f);
  cvt_kernel<<<4096, 256, 0, stream>>>(Wo,  wob,           4194304L, 1.0f);
  cvt_kernel<<<1024, 256, 0, stream>>>(Wuk, wukb,          1048576L, 1.0f);
  cvt_kernel<<<1024, 256, 0, stream>>>(Wuv, wuvb,          1048576L, 1.0f);

  // fused q|lat = x @ [Wq' | Wd]^T : [4096, 2560]   (grid: x = N/256 = 10, y = M/256 = 16)
  gemm256<1><<<dim3(10, 16), 512, 0, stream>>>(xb, wqdb, qlat, 2048, 2048, 2048, 2560, 1.0f);
  // k = lat @ Wuk^T : [4096, 2048]   (lat = qlat cols 2048.., lda 2560)
  gemm256<1><<<dim3(8, 16), 512, 0, stream>>>(qlat + 2048, wukb, kb, 512, 2560, 512, 2048, 1.0f);
  // vT = Wuv @ lat^T : [2048(h,d)][4096(b,t)]
  gemm256<1><<<dim3(16, 8), 512, 0, stream>>>(wuvb, qlat + 2048, vTb, 512, 512, 2560, 4096, 1.0f);
  // flash attention (causal, d=128): attnO [4096][2048]
  flash12_kernel<<<512, 256, 0, stream>>>(qlat, kb, vTb, attnO);
  // out = attnO @ Wo^T : fp32 [4096, 2048]
  gemm256<0><<<dim3(8, 16), 512, 0, stream>>>(attnO, wob, out, 2048, 2048, 2048, 2048, 1.0f);
}

// Round 14
// 236.530 us; speedup vs baseline: 1.2504x; 1.2504x over previous
//
#include <hip/hip_runtime.h>
#include <hip/hip_bf16.h>

typedef __attribute__((ext_vector_type(8))) short short8x;   // 8 x bf16 (4 VGPR) MFMA A/B frag
typedef __attribute__((ext_vector_type(4))) float f32x4;     // MFMA C/D frag

__device__ __forceinline__ ushort f2bf(float f){
  union { __hip_bfloat16 b; ushort u; } cvt;
  cvt.b = __float2bfloat16(f);                // RNE
  return cvt.u;
}

// ---------------- elementwise fp32 -> bf16 (optional scale) ----------------
__global__ __launch_bounds__(256) void cvt_kernel(const float* __restrict__ in, ushort* __restrict__ out,
                                                  long n, float scale){
  long i = ((long)blockIdx.x * 256 + threadIdx.x) * 4;
  if (i >= n) return;
  float4 v = *(const float4*)(in + i);
  ushort4 o;
  o.x = f2bf(v.x * scale); o.y = f2bf(v.y * scale); o.z = f2bf(v.z * scale); o.w = f2bf(v.w * scale);
  *(ushort4*)(out + i) = o;
}

// ---------------- generic bf16 GEMM: C = A[M,K] * B  with B given as BT[N,K] ----------------
// 128x128 tile, BK=32, 4 waves (2x2), double-buffered LDS staged via global_load_lds(16B).
// XCD-aware block swizzle (T1). REVERTED to the round-12 proven version (gemm256 regressed:
// grid underfill at 256^2 tiles + double fragment reads + coarse lgkm drains, m196's lesson).
template<int OUTBF>
__global__ __launch_bounds__(256, 3)
void gemm_bt(const ushort* __restrict__ A, const ushort* __restrict__ BT, void* __restrict__ Cv,
             int M, int N, int K, int lda, int ldb, int ldc,
             long aZ, long bZ, long cZ, float scale)
{
  __shared__ __align__(16) ushort As[2][128 * 32];
  __shared__ __align__(16) ushort Bs[2][128 * 32];
  const int z = blockIdx.z;
  const ushort* Ab = A + (long)z * aZ;
  const ushort* Bb = BT + (long)z * bZ;
  const int tid = threadIdx.x, lane = tid & 63, w = tid >> 6;
  const int wm = w >> 1, wn = w & 1;
  const int lq = lane & 15, q4 = lane >> 4;

  int lin = blockIdx.x + gridDim.x * blockIdx.y;
  const int cpx = (gridDim.x * gridDim.y) >> 3;
  lin = (lin & 7) * cpx + (lin >> 3);
  const int bx = lin % gridDim.x, by = lin / gridDim.x;

  const long arow = (long)by * 128, brow = (long)bx * 128;
  const int lr = lane >> 2, lc = (lane & 3) * 8;

  const f32x4 z4 = {0.f, 0.f, 0.f, 0.f};
  f32x4 acc[4][4];
#pragma unroll
  for (int i = 0; i < 4; i++)
#pragma unroll
    for (int j = 0; j < 4; j++) acc[i][j] = z4;

  auto stage = [&](int buf, int k0){
#pragma unroll
    for (int is = 0; is < 2; ++is){
      const int rb = is * 64 + w * 16;
      const ushort* ga = Ab + (arow + rb + lr) * (long)lda + k0 + lc;
      const ushort* gb = Bb + (brow + rb + lr) * (long)ldb + k0 + lc;
      __builtin_amdgcn_global_load_lds((const __attribute__((address_space(1))) void*)ga,
                                       (__attribute__((address_space(3))) void*)&As[buf][rb * 32], 16, 0, 0);
      __builtin_amdgcn_global_load_lds((const __attribute__((address_space(1))) void*)gb,
                                       (__attribute__((address_space(3))) void*)&Bs[buf][rb * 32], 16, 0, 0);
    }
  };

  const int nk = K >> 5;
  stage(0, 0);
  for (int kt = 0; kt < nk; ++kt){
    __syncthreads();
    if (kt + 1 < nk) stage((kt + 1) & 1, (kt + 1) * 32);
    const int buf = kt & 1;
    short8x a[4], b[4];
#pragma unroll
    for (int i = 0; i < 4; i++){
      a[i] = *(const short8x*)&As[buf][(wm * 64 + i * 16 + lq) * 32 + q4 * 8];
      b[i] = *(const short8x*)&Bs[buf][(wn * 64 + i * 16 + lq) * 32 + q4 * 8];
    }
#pragma unroll
    for (int i = 0; i < 4; i++)
#pragma unroll
      for (int j = 0; j < 4; j++)
        acc[i][j] = __builtin_amdgcn_mfma_f32_16x16x32_bf16(a[i], b[j], acc[i][j], 0, 0, 0);
  }

  const long crowb = arow + wm * 64;
  const long ccolb = brow + wn * 64;
#pragma unroll
  for (int i = 0; i < 4; i++)
#pragma unroll
    for (int j = 0; j < 4; j++)
#pragma unroll
      for (int r = 0; r < 4; r++){
        const long row = crowb + i * 16 + q4 * 4 + r;
        const long col = ccolb + j * 16 + lq;
        const float v = acc[i][j][r] * scale;
        if (OUTBF) ((ushort*)Cv)[(long)z * cZ + row * ldc + col] = f2bf(v);
        else       ((float*)Cv)[(long)z * cZ + row * ldc + col] = v;
      }
}

// ---------------- flash attention v13: deep TLP — 1024 blocks, 4/CU, KVBLK=32 ---------------
// 4 waves x 16 q-rows (64 rows/block); LDS 37KB -> 4 independent blocks co-resident per CU
// (16 waves/CU): unsynchronized streams hide each other's vmcnt/barrier/chain stalls — the
// lever rounds 5-12 showed is the ONLY one that works for this latency-bound loop.
// Mapping: bh = (blk&7)*4 + ((blk>>3)&3) keeps each (b,h) on one XCD (verified FETCH 24.6MB);
// g = blk>>5, slot u = (g&7)*4 + (g>>3), strip = zigzag(u) -> round-robin sets {c,c+256,
// c+512,c+768} get strips summing to 134 steps on every CU (balanced).
// Per step: QK (8 ds_read + 8 MFMA) -> exp2+pack -> lgkm -> PV (pf b128 + 8 V reads + 8 MFMA).
// K-tile granule^(row&7) swizzle (both sides); V linear 64B rows (flash5-proven); Pl padded 40.
// Depth-2 staging, counted vmcnt(4). q from fused q|lat (stride 2560), exp2-folded Wq.
__global__ __launch_bounds__(256, 4)
void flash13_kernel(const ushort* __restrict__ q, const ushort* __restrict__ k,
                    const ushort* __restrict__ vT, ushort* __restrict__ attnO)
{
  __shared__ __align__(16) ushort Kb[2][32 * 128];   // [t][d] swizzled granules, 8KB each
  __shared__ __align__(16) ushort Vb[2][128 * 32];   // [d][t] linear 64B rows, 8KB each
  __shared__ __align__(16) ushort Pl[4][16][40];     // [w][s][t+pad], 5KB

  const int tid = threadIdx.x, lane = tid & 63, w = tid >> 6;   // w = 0..3
  const int lq = lane & 15, q4 = lane >> 4;

  const int blk = blockIdx.x;
  const int bh = (blk & 7) * 4 + ((blk >> 3) & 3);
  const int g = blk >> 5;                    // 0..31
  const int u = (g & 7) * 4 + (g >> 3);      // slot id; {g,g+8,g+16,g+24} -> consecutive u
  const int strip = (u & 1) ? (u >> 1) : (31 - (u >> 1));   // zigzag: balanced per-CU sums
  const int b = bh & 1, h = bh >> 1;

  const int nt = 2 * strip + 2;              // 32-wide t-tiles staged by this block
  const int wdiag = strip * 2 + (w >> 1);    // wave's diagonal tile
  const int moff = (w & 1) * 16;             // wave's row offset within diag tile

  const ushort* kb_ = k + (long)b * 2048 * 2048 + h * 128;        // row t stride 2048
  const ushort* vb_ = vT + (long)h * 128 * 4096 + (long)b * 2048; // row d stride 4096

  // hoisted staging addresses (is-offsets compile-time; K swizzle is-invariant)
  const int krow0 = w * 4 + (lane >> 4);                          // is adds 16
  const int kg = (lane & 15) ^ (krow0 & 7);
  const ushort* kbase = kb_ + (long)krow0 * 2048 + kg * 8;

  const int drow0 = w * 16 + (lane >> 2);                         // is adds 64
  const ushort* vbase = vb_ + (long)drow0 * 4096 + (lane & 3) * 8;

  auto stage = [&](int buf, int tt){
    const ushort* kp = kbase + (long)tt * 32 * 2048;
    const ushort* vp = vbase + (long)tt * 32;
#pragma unroll
    for (int is = 0; is < 2; ++is){
      __builtin_amdgcn_global_load_lds((const __attribute__((address_space(1))) void*)(kp + (long)is * 16 * 2048),
          (__attribute__((address_space(3))) void*)&Kb[buf][w * 512 + is * 2048], 16, 0, 0);
      __builtin_amdgcn_global_load_lds((const __attribute__((address_space(1))) void*)(vp + (long)is * 64 * 4096),
          (__attribute__((address_space(3))) void*)&Vb[buf][w * 512 + is * 2048], 16, 0, 0);
    }
  };

  const f32x4 z4 = {0.f, 0.f, 0.f, 0.f};

  const int qrow0 = strip * 64 + w * 16;
  const long qgbase = (long)b * 2048 + qrow0;

  // Q B-frags (16 rows): s = qrow0+lq, d = ks*32+q4*8+j ; fused q|lat buffer stride 2560
  short8x qf[4];
  {
    const ushort* qp = q + (qgbase + lq) * 2560 + h * 128 + q4 * 8;
#pragma unroll
    for (int ks = 0; ks < 4; ks++) qf[ks] = *(const short8x*)(qp + ks * 32);
  }

  f32x4 oacc[8];                             // O^T[d = dt*16 + q4*4 + r][s = lq]
#pragma unroll
  for (int dt = 0; dt < 8; dt++) oacc[dt] = z4;
  float dsum = 0.f;

  stage(0, 0);
  stage(1, 1);          // nt >= 2 always

#pragma unroll 1
  for (int tt = 0; tt < nt; ++tt){
    if (tt == nt - 1) asm volatile("s_waitcnt vmcnt(0)" ::: "memory");
    else              asm volatile("s_waitcnt vmcnt(4)" ::: "memory");
    __syncthreads();
    const int cur = tt & 1;

    if (tt <= wdiag){
      const bool diag = (tt == wdiag);
      // QK + exp2 + pack, per ti (t-subtile of 16)
#pragma unroll
      for (int ti = 0; ti < 2; ++ti){
        const int r = ti * 16 + lq;
        const int rb = r * 128;
        const int rx = lq & 7;
        const short8x a0 = *(const short8x*)&Kb[cur][rb + (((q4) ^ rx) * 8)];
        const short8x a1 = *(const short8x*)&Kb[cur][rb + (((4 + q4) ^ rx) * 8)];
        const short8x a2 = *(const short8x*)&Kb[cur][rb + (((8 + q4) ^ rx) * 8)];
        const short8x a3 = *(const short8x*)&Kb[cur][rb + (((12 + q4) ^ rx) * 8)];
        f32x4 st = __builtin_amdgcn_mfma_f32_16x16x32_bf16(a0, qf[0], z4, 0, 0, 0);
        st = __builtin_amdgcn_mfma_f32_16x16x32_bf16(a1, qf[1], st, 0, 0, 0);
        st = __builtin_amdgcn_mfma_f32_16x16x32_bf16(a2, qf[2], st, 0, 0, 0);
        st = __builtin_amdgcn_mfma_f32_16x16x32_bf16(a3, qf[3], st, 0, 0, 0);
        ushort4 pb;
#pragma unroll
        for (int r4 = 0; r4 < 4; ++r4){
          const int tl = ti * 16 + q4 * 4 + r4;
          float p = exp2f(st[r4]);
          if (diag && tl > moff + lq) p = 0.f;
          dsum += p;
          ((ushort*)&pb)[r4] = f2bf(p);
        }
        *(ushort4*)&Pl[w][lq][ti * 16 + q4 * 4] = pb;
      }
      asm volatile("s_waitcnt lgkmcnt(0)" ::: "memory");
      __builtin_amdgcn_sched_barrier(0);
      const short8x pf = *(const short8x*)&Pl[w][lq][q4 * 8];   // P^T[t=q4*8+j][s=lq]
      __builtin_amdgcn_sched_barrier(0);
      // PV: O^T[d][s] += V^T[d][t] * P^T[t][s], k=32
#pragma unroll
      for (int dt = 0; dt < 8; ++dt){
        const short8x av = *(const short8x*)&Vb[cur][(dt * 16 + lq) * 32 + q4 * 8];
        oacc[dt] = __builtin_amdgcn_mfma_f32_16x16x32_bf16(av, pf, oacc[dt], 0, 0, 0);
      }
    }
    __syncthreads();                        // all reads of buf[cur] complete
    if (tt + 2 < nt) stage(cur, tt + 2);    // overwrite buf[cur] = buf[(tt+2)&1]
  }

  dsum += __shfl_xor(dsum, 16);
  dsum += __shfl_xor(dsum, 32);
  const float inv = 1.f / dsum;

#pragma unroll
  for (int dt = 0; dt < 8; dt++){
    ushort4 o;
    o.x = f2bf(oacc[dt][0] * inv);
    o.y = f2bf(oacc[dt][1] * inv);
    o.z = f2bf(oacc[dt][2] * inv);
    o.w = f2bf(oacc[dt][3] * inv);
    *(ushort4*)(attnO + (qgbase + lq) * 2048 + h * 128 + dt * 16 + q4 * 4) = o;
  }
}

// ---------------- host launcher ----------------
extern "C" void kernel_launch(void* const* d_in, const int* in_sizes, int n_in,
                              void* d_out, int out_size, void* d_ws, size_t ws_size,
                              hipStream_t stream)
{
  const float* x   = (const float*)d_in[0];
  const float* Wd  = (const float*)d_in[1];
  const float* Wuk = (const float*)d_in[2];
  const float* Wuv = (const float*)d_in[3];
  const float* Wq  = (const float*)d_in[4];
  const float* Wo  = (const float*)d_in[5];
  float* out = (float*)d_out;
  ushort* ws = (ushort*)d_ws;

  ushort* xb    = ws + 0L;          // [4096][2048]
  ushort* wqdb  = ws + 8388608L;    // [2560][2048]: rows 0..2047 = Wq*(log2e/sqrt(128)), 2048..2559 = Wd
  ushort* wob   = ws + 13631488L;   // [2048(m)][2048(h,d)]
  ushort* wukb  = ws + 17825792L;   // [2048(h,d)][512(c)]
  ushort* wuvb  = ws + 18874368L;   // [2048(h,d)][512(c)]
  ushort* qlat  = ws + 19922944L;   // [4096][2560]: cols 0..2047 = q (pre-scaled), 2048..2559 = lat
  ushort* kb    = ws + 30408704L;   // [4096(b,t)][2048(h,d)]
  ushort* vTb   = ws + 38797312L;   // [2048(h,d)][4096(b,t)]
  ushort* attnO = ws + 47185920L;   // [4096(b,s)][2048(h,d)]

  // log2(e)/sqrt(128): folded into Wq so flash uses exp2 (identical softmax)
  const float QSCL = 0.12751744800f;

  cvt_kernel<<<8192, 256, 0, stream>>>(x,   xb,            8388608L, 1.0f);
  cvt_kernel<<<4096, 256, 0, stream>>>(Wq,  wqdb,          4194304L, QSCL);
  cvt_kernel<<<1024, 256, 0, stream>>>(Wd,  wqdb + 4194304L, 1048576L, 1.0f);
  cvt_kernel<<<4096, 256, 0, stream>>>(Wo,  wob,           4194304L, 1.0f);
  cvt_kernel<<<1024, 256, 0, stream>>>(Wuk, wukb,          1048576L, 1.0f);
  cvt_kernel<<<1024, 256, 0, stream>>>(Wuv, wuvb,          1048576L, 1.0f);

  // fused q|lat = x @ [Wq' | Wd]^T : [4096, 2560]
  gemm_bt<1><<<dim3(20, 32, 1), 256, 0, stream>>>(xb, wqdb, qlat, 4096, 2560, 2048,
      2048, 2048, 2560, 0L, 0L, 0L, 1.0f);
  // k = lat @ Wuk^T : [4096, 2048]   (lat = qlat cols 2048.., lda 2560)
  gemm_bt<1><<<dim3(16, 32, 1), 256, 0, stream>>>(qlat + 2048, wukb, kb, 4096, 2048, 512,
      2560, 512, 2048, 0L, 0L, 0L, 1.0f);
  // vT = Wuv @ lat^T : [2048(h,d)][4096(b,t)]
  gemm_bt<1><<<dim3(32, 16, 1), 256, 0, stream>>>(wuvb, qlat + 2048, vTb, 2048, 4096, 512,
      512, 2560, 4096, 0L, 0L, 0L, 1.0f);
  // flash attention (causal, d=128): attnO [4096][2048]
  flash13_kernel<<<1024, 256, 0, stream>>>(qlat, kb, vTb, attnO);
  // out = attnO @ Wo^T : fp32 [4096, 2048]
  gemm_bt<0><<<dim3(16, 32, 1), 256, 0, stream>>>(attnO, wob, out, 4096, 2048, 2048,
      2048, 2048, 2048, 0L, 0L, 0L, 1.0f);
}

// Round 15
// 235.226 us; speedup vs baseline: 1.2573x; 1.0055x over previous
//
#include <hip/hip_runtime.h>
#include <hip/hip_bf16.h>

typedef __attribute__((ext_vector_type(8))) short short8x;   // 8 x bf16 (4 VGPR) MFMA A/B frag
typedef __attribute__((ext_vector_type(4))) float f32x4;     // MFMA C/D frag

__device__ __forceinline__ ushort f2bf(float f){
  union { __hip_bfloat16 b; ushort u; } cvt;
  cvt.b = __float2bfloat16(f);                // RNE
  return cvt.u;
}

// ---------------- elementwise fp32 -> bf16 (optional scale) ----------------
__global__ __launch_bounds__(256) void cvt_kernel(const float* __restrict__ in, ushort* __restrict__ out,
                                                  long n, float scale){
  long i = ((long)blockIdx.x * 256 + threadIdx.x) * 4;
  if (i >= n) return;
  float4 v = *(const float4*)(in + i);
  ushort4 o;
  o.x = f2bf(v.x * scale); o.y = f2bf(v.y * scale); o.z = f2bf(v.z * scale); o.w = f2bf(v.w * scale);
  *(ushort4*)(out + i) = o;
}

// ---------------- generic bf16 GEMM: C = A[M,K] * B  with B given as BT[N,K] ----------------
// 128x128 tile, BK=32, 4 waves (2x2), double-buffered LDS staged via global_load_lds(16B).
// XCD-aware block swizzle (T1). Round-12 proven version.
template<int OUTBF>
__global__ __launch_bounds__(256, 3)
void gemm_bt(const ushort* __restrict__ A, const ushort* __restrict__ BT, void* __restrict__ Cv,
             int M, int N, int K, int lda, int ldb, int ldc,
             long aZ, long bZ, long cZ, float scale)
{
  __shared__ __align__(16) ushort As[2][128 * 32];
  __shared__ __align__(16) ushort Bs[2][128 * 32];
  const int z = blockIdx.z;
  const ushort* Ab = A + (long)z * aZ;
  const ushort* Bb = BT + (long)z * bZ;
  const int tid = threadIdx.x, lane = tid & 63, w = tid >> 6;
  const int wm = w >> 1, wn = w & 1;
  const int lq = lane & 15, q4 = lane >> 4;

  int lin = blockIdx.x + gridDim.x * blockIdx.y;
  const int cpx = (gridDim.x * gridDim.y) >> 3;
  lin = (lin & 7) * cpx + (lin >> 3);
  const int bx = lin % gridDim.x, by = lin / gridDim.x;

  const long arow = (long)by * 128, brow = (long)bx * 128;
  const int lr = lane >> 2, lc = (lane & 3) * 8;

  const f32x4 z4 = {0.f, 0.f, 0.f, 0.f};
  f32x4 acc[4][4];
#pragma unroll
  for (int i = 0; i < 4; i++)
#pragma unroll
    for (int j = 0; j < 4; j++) acc[i][j] = z4;

  auto stage = [&](int buf, int k0){
#pragma unroll
    for (int is = 0; is < 2; ++is){
      const int rb = is * 64 + w * 16;
      const ushort* ga = Ab + (arow + rb + lr) * (long)lda + k0 + lc;
      const ushort* gb = Bb + (brow + rb + lr) * (long)ldb + k0 + lc;
      __builtin_amdgcn_global_load_lds((const __attribute__((address_space(1))) void*)ga,
                                       (__attribute__((address_space(3))) void*)&As[buf][rb * 32], 16, 0, 0);
      __builtin_amdgcn_global_load_lds((const __attribute__((address_space(1))) void*)gb,
                                       (__attribute__((address_space(3))) void*)&Bs[buf][rb * 32], 16, 0, 0);
    }
  };

  const int nk = K >> 5;
  stage(0, 0);
  for (int kt = 0; kt < nk; ++kt){
    __syncthreads();
    if (kt + 1 < nk) stage((kt + 1) & 1, (kt + 1) * 32);
    const int buf = kt & 1;
    short8x a[4], b[4];
#pragma unroll
    for (int i = 0; i < 4; i++){
      a[i] = *(const short8x*)&As[buf][(wm * 64 + i * 16 + lq) * 32 + q4 * 8];
      b[i] = *(const short8x*)&Bs[buf][(wn * 64 + i * 16 + lq) * 32 + q4 * 8];
    }
#pragma unroll
    for (int i = 0; i < 4; i++)
#pragma unroll
      for (int j = 0; j < 4; j++)
        acc[i][j] = __builtin_amdgcn_mfma_f32_16x16x32_bf16(a[i], b[j], acc[i][j], 0, 0, 0);
  }

  const long crowb = arow + wm * 64;
  const long ccolb = brow + wn * 64;
#pragma unroll
  for (int i = 0; i < 4; i++)
#pragma unroll
    for (int j = 0; j < 4; j++)
#pragma unroll
      for (int r = 0; r < 4; r++){
        const long row = crowb + i * 16 + q4 * 4 + r;
        const long col = ccolb + j * 16 + lq;
        const float v = acc[i][j][r] * scale;
        if (OUTBF) ((ushort*)Cv)[(long)z * cZ + row * ldc + col] = f2bf(v);
        else       ((float*)Cv)[(long)z * cZ + row * ldc + col] = v;
      }
}

// ---------------- flash attention v14: flash13 + V granule-XOR swizzle (conflict fix) -------
// Round-14 diagnosis: flash13's V read (64B rows, linear) is an 8-way bank conflict -> 10.1M
// conflict cycles = ~45% of LDS pipe. Fix (rule #21, both sides): LDS slot (r, gL) holds
// global granule gL ^ ((r>>1)&3) via pre-swizzled global source; read slot q4 ^ ((lq>>1)&3).
// Bank base = (lq&1)*16 + (q4^((lq>>1)&3))*4 -> 8 bases covering 32 banks 2-way = free.
// Everything else identical to flash13 (1024 blocks, 4/CU, KVBLK=32, zigzag LPT, XCD-local).
__global__ __launch_bounds__(256, 4)
void flash14_kernel(const ushort* __restrict__ q, const ushort* __restrict__ k,
                    const ushort* __restrict__ vT, ushort* __restrict__ attnO)
{
  __shared__ __align__(16) ushort Kb[2][32 * 128];   // [t][d] swizzled granules, 8KB each
  __shared__ __align__(16) ushort Vb[2][128 * 32];   // [d][t] granule-XOR swizzled, 8KB each
  __shared__ __align__(16) ushort Pl[4][16][40];     // [w][s][t+pad], 5KB

  const int tid = threadIdx.x, lane = tid & 63, w = tid >> 6;   // w = 0..3
  const int lq = lane & 15, q4 = lane >> 4;

  const int blk = blockIdx.x;
  const int bh = (blk & 7) * 4 + ((blk >> 3) & 3);
  const int g = blk >> 5;                    // 0..31
  const int u = (g & 7) * 4 + (g >> 3);      // slot id; {g,g+8,g+16,g+24} -> consecutive u
  const int strip = (u & 1) ? (u >> 1) : (31 - (u >> 1));   // zigzag: balanced per-CU sums
  const int b = bh & 1, h = bh >> 1;

  const int nt = 2 * strip + 2;              // 32-wide t-tiles staged by this block
  const int wdiag = strip * 2 + (w >> 1);    // wave's diagonal tile
  const int moff = (w & 1) * 16;             // wave's row offset within diag tile

  const ushort* kb_ = k + (long)b * 2048 * 2048 + h * 128;        // row t stride 2048
  const ushort* vb_ = vT + (long)h * 128 * 4096 + (long)b * 2048; // row d stride 4096

  // hoisted staging addresses (is-offsets compile-time; both swizzles is/w-invariant)
  const int krow0 = w * 4 + (lane >> 4);                          // is adds 16
  const int kg = (lane & 15) ^ (krow0 & 7);
  const ushort* kbase = kb_ + (long)krow0 * 2048 + kg * 8;

  const int drow0 = w * 16 + (lane >> 2);                         // is adds 64
  const int vg = (lane & 3) ^ ((lane >> 3) & 3);                  // = (lane&3) ^ ((drow0>>1)&3)
  const ushort* vbase = vb_ + (long)drow0 * 4096 + vg * 8;

  auto stage = [&](int buf, int tt){
    const ushort* kp = kbase + (long)tt * 32 * 2048;
    const ushort* vp = vbase + (long)tt * 32;
#pragma unroll
    for (int is = 0; is < 2; ++is){
      __builtin_amdgcn_global_load_lds((const __attribute__((address_space(1))) void*)(kp + (long)is * 16 * 2048),
          (__attribute__((address_space(3))) void*)&Kb[buf][w * 512 + is * 2048], 16, 0, 0);
      __builtin_amdgcn_global_load_lds((const __attribute__((address_space(1))) void*)(vp + (long)is * 64 * 4096),
          (__attribute__((address_space(3))) void*)&Vb[buf][w * 512 + is * 2048], 16, 0, 0);
    }
  };

  const f32x4 z4 = {0.f, 0.f, 0.f, 0.f};

  const int qrow0 = strip * 64 + w * 16;
  const long qgbase = (long)b * 2048 + qrow0;

  // Q B-frags (16 rows): s = qrow0+lq, d = ks*32+q4*8+j ; fused q|lat buffer stride 2560
  short8x qf[4];
  {
    const ushort* qp = q + (qgbase + lq) * 2560 + h * 128 + q4 * 8;
#pragma unroll
    for (int ks = 0; ks < 4; ks++) qf[ks] = *(const short8x*)(qp + ks * 32);
  }

  f32x4 oacc[8];                             // O^T[d = dt*16 + q4*4 + r][s = lq]
#pragma unroll
  for (int dt = 0; dt < 8; dt++) oacc[dt] = z4;
  float dsum = 0.f;

  const int rxv = (lq >> 1) & 3;             // V read-side swizzle key ((r>>1)&3, dt-invariant)

  stage(0, 0);
  stage(1, 1);          // nt >= 2 always

#pragma unroll 1
  for (int tt = 0; tt < nt; ++tt){
    if (tt == nt - 1) asm volatile("s_waitcnt vmcnt(0)" ::: "memory");
    else              asm volatile("s_waitcnt vmcnt(4)" ::: "memory");
    __syncthreads();
    const int cur = tt & 1;

    if (tt <= wdiag){
      const bool diag = (tt == wdiag);
      // QK + exp2 + pack, per ti (t-subtile of 16)
#pragma unroll
      for (int ti = 0; ti < 2; ++ti){
        const int r = ti * 16 + lq;
        const int rb = r * 128;
        const int rx = lq & 7;
        const short8x a0 = *(const short8x*)&Kb[cur][rb + (((q4) ^ rx) * 8)];
        const short8x a1 = *(const short8x*)&Kb[cur][rb + (((4 + q4) ^ rx) * 8)];
        const short8x a2 = *(const short8x*)&Kb[cur][rb + (((8 + q4) ^ rx) * 8)];
        const short8x a3 = *(const short8x*)&Kb[cur][rb + (((12 + q4) ^ rx) * 8)];
        f32x4 st = __builtin_amdgcn_mfma_f32_16x16x32_bf16(a0, qf[0], z4, 0, 0, 0);
        st = __builtin_amdgcn_mfma_f32_16x16x32_bf16(a1, qf[1], st, 0, 0, 0);
        st = __builtin_amdgcn_mfma_f32_16x16x32_bf16(a2, qf[2], st, 0, 0, 0);
        st = __builtin_amdgcn_mfma_f32_16x16x32_bf16(a3, qf[3], st, 0, 0, 0);
        ushort4 pb;
#pragma unroll
        for (int r4 = 0; r4 < 4; ++r4){
          const int tl = ti * 16 + q4 * 4 + r4;
          float p = exp2f(st[r4]);
          if (diag && tl > moff + lq) p = 0.f;
          dsum += p;
          ((ushort*)&pb)[r4] = f2bf(p);
        }
        *(ushort4*)&Pl[w][lq][ti * 16 + q4 * 4] = pb;
      }
      asm volatile("s_waitcnt lgkmcnt(0)" ::: "memory");
      __builtin_amdgcn_sched_barrier(0);
      const short8x pf = *(const short8x*)&Pl[w][lq][q4 * 8];   // P^T[t=q4*8+j][s=lq]
      __builtin_amdgcn_sched_barrier(0);
      // PV: O^T[d][s] += V^T[d][t] * P^T[t][s], k=32; V at swizzled granule q4^rxv
#pragma unroll
      for (int dt = 0; dt < 8; ++dt){
        const short8x av = *(const short8x*)&Vb[cur][(dt * 16 + lq) * 32 + ((q4 ^ rxv) * 8)];
        oacc[dt] = __builtin_amdgcn_mfma_f32_16x16x32_bf16(av, pf, oacc[dt], 0, 0, 0);
      }
    }
    __syncthreads();                        // all reads of buf[cur] complete
    if (tt + 2 < nt) stage(cur, tt + 2);    // overwrite buf[cur] = buf[(tt+2)&1]
  }

  dsum += __shfl_xor(dsum, 16);
  dsum += __shfl_xor(dsum, 32);
  const float inv = 1.f / dsum;

#pragma unroll
  for (int dt = 0; dt < 8; dt++){
    ushort4 o;
    o.x = f2bf(oacc[dt][0] * inv);
    o.y = f2bf(oacc[dt][1] * inv);
    o.z = f2bf(oacc[dt][2] * inv);
    o.w = f2bf(oacc[dt][3] * inv);
    *(ushort4*)(attnO + (qgbase + lq) * 2048 + h * 128 + dt * 16 + q4 * 4) = o;
  }
}

// ---------------- host launcher ----------------
extern "C" void kernel_launch(void* const* d_in, const int* in_sizes, int n_in,
                              void* d_out, int out_size, void* d_ws, size_t ws_size,
                              hipStream_t stream)
{
  const float* x   = (const float*)d_in[0];
  const float* Wd  = (const float*)d_in[1];
  const float* Wuk = (const float*)d_in[2];
  const float* Wuv = (const float*)d_in[3];
  const float* Wq  = (const float*)d_in[4];
  const float* Wo  = (const float*)d_in[5];
  float* out = (float*)d_out;
  ushort* ws = (ushort*)d_ws;

  ushort* xb    = ws + 0L;          // [4096][2048]
  ushort* wqdb  = ws + 8388608L;    // [2560][2048]: rows 0..2047 = Wq*(log2e/sqrt(128)), 2048..2559 = Wd
  ushort* wob   = ws + 13631488L;   // [2048(m)][2048(h,d)]
  ushort* wukb  = ws + 17825792L;   // [2048(h,d)][512(c)]
  ushort* wuvb  = ws + 18874368L;   // [2048(h,d)][512(c)]
  ushort* qlat  = ws + 19922944L;   // [4096][2560]: cols 0..2047 = q (pre-scaled), 2048..2559 = lat
  ushort* kb    = ws + 30408704L;   // [4096(b,t)][2048(h,d)]
  ushort* vTb   = ws + 38797312L;   // [2048(h,d)][4096(b,t)]
  ushort* attnO = ws + 47185920L;   // [4096(b,s)][2048(h,d)]

  // log2(e)/sqrt(128): folded into Wq so flash uses exp2 (identical softmax)
  const float QSCL = 0.12751744800f;

  cvt_kernel<<<8192, 256, 0, stream>>>(x,   xb,            8388608L, 1.0f);
  cvt_kernel<<<4096, 256, 0, stream>>>(Wq,  wqdb,          4194304L, QSCL);
  cvt_kernel<<<1024, 256, 0, stream>>>(Wd,  wqdb + 4194304L, 1048576L, 1.0f);
  cvt_kernel<<<4096, 256, 0, stream>>>(Wo,  wob,           4194304L, 1.0f);
  cvt_kernel<<<1024, 256, 0, stream>>>(Wuk, wukb,          1048576L, 1.0f);
  cvt_kernel<<<1024, 256, 0, stream>>>(Wuv, wuvb,          1048576L, 1.0f);

  // fused q|lat = x @ [Wq' | Wd]^T : [4096, 2560]
  gemm_bt<1><<<dim3(20, 32, 1), 256, 0, stream>>>(xb, wqdb, qlat, 4096, 2560, 2048,
      2048, 2048, 2560, 0L, 0L, 0L, 1.0f);
  // k = lat @ Wuk^T : [4096, 2048]   (lat = qlat cols 2048.., lda 2560)
  gemm_bt<1><<<dim3(16, 32, 1), 256, 0, stream>>>(qlat + 2048, wukb, kb, 4096, 2048, 512,
      2560, 512, 2048, 0L, 0L, 0L, 1.0f);
  // vT = Wuv @ lat^T : [2048(h,d)][4096(b,t)]
  gemm_bt<1><<<dim3(32, 16, 1), 256, 0, stream>>>(wuvb, qlat + 2048, vTb, 2048, 4096, 512,
      512, 2560, 4096, 0L, 0L, 0L, 1.0f);
  // flash attention (causal, d=128): attnO [4096][2048]
  flash14_kernel<<<1024, 256, 0, stream>>>(qlat, kb, vTb, attnO);
  // out = attnO @ Wo^T : fp32 [4096, 2048]
  gemm_bt<0><<<dim3(16, 32, 1), 256, 0, stream>>>(attnO, wob, out, 4096, 2048, 2048,
      2048, 2048, 2048, 0L, 0L, 0L, 1.0f);
}